// Round 3
// baseline (5268.464 us; speedup 1.0000x reference)
//
#include <hip/hip_runtime.h>

typedef __attribute__((ext_vector_type(8))) short bf16x8;
typedef __attribute__((ext_vector_type(4))) float f32x4;
typedef __attribute__((ext_vector_type(2))) float f32x2;

constexpr int   HD      = 128;
constexpr float T_NEAR  = 0.2f;
constexpr float T_FAR   = 2.0f;
constexpr float ALPHA_C = 100.0f;
constexpr int   MARCH_N = 32;
constexpr float HIT_EPS = 0.005f;
constexpr int   TP_N    = 32;
constexpr float STEP    = 0.0634765625f;  // (2.0 + 0.5*(2/32))/32, exact

// ---------- bf16 helpers ----------
__device__ __forceinline__ unsigned short f2bf(float x) {
  unsigned u = __float_as_uint(x);
  unsigned r = 0x7fffu + ((u >> 16) & 1u);
  return (unsigned short)((u + r) >> 16);
}

union U8 { bf16x8 v; uint4 u4; unsigned short us[8]; };

// packed fp32 fma: d = a*b + c (VOP3P, 1 instr for 2 floats)
__device__ __forceinline__ f32x2 pk_fma(f32x2 a, f32x2 b, f32x2 c) {
  f32x2 d;
  asm("v_pk_fma_f32 %0, %1, %2, %3" : "=v"(d) : "v"(a), "v"(b), "v"(c));
  return d;
}

// {h.x,h.y} -> packed bf16 pair (round-half-up) with relu applied in bf16-bit
// domain (max_i16 vs 0 zeroes any negative bf16; sign-exact).
__device__ __forceinline__ unsigned pack_relu_pair(f32x2 h) {
  unsigned u0 = __float_as_uint(h.x) + 0x8000u;
  unsigned u1 = __float_as_uint(h.y) + 0x8000u;
  unsigned w, r;
  asm("v_perm_b32 %0, %1, %2, %3" : "=v"(w) : "v"(u1), "v"(u0), "s"(0x07060302u));
  asm("v_pk_max_i16 %0, %1, %2" : "=v"(r) : "v"(w), "v"(0u));
  return r;
}

// ---------- setup kernel: pack W2^T into per-lane MFMA A-fragments ----------
__global__ void pack_w2(const float* __restrict__ W2,
                        unsigned short* __restrict__ hi,
                        unsigned short* __restrict__ lo) {
  int idx = blockIdx.x * 256 + threadIdx.x;     // 0..16383
  int j = idx & 7, l = (idx >> 3) & 63, t = (idx >> 9) & 7, s = idx >> 12;
  int m = 16 * t + (l & 15);
  int k = 32 * s + (l >> 4) * 8 + j;
  float w = W2[k * HD + m];
  unsigned short h = f2bf(w);
  float hf = __uint_as_float(((unsigned)h) << 16);
  hi[idx] = h;
  lo[idx] = f2bf(w - hf);
}

// ---------- shared epilogue: relu + W3 dot + cross-quad reduce (bit-identical) ----------
// W3 pairs from this wave's private LDS copy (lw + 128).
__device__ __forceinline__ float sdf_reduce(const f32x4 (&acc)[8],
                                            const float* lw, int q, float b3v) {
  f32x2 e0; e0.x = 0.f; e0.y = 0.f;
  f32x2 e1 = e0, e2 = e0, e3 = e0;
  #pragma unroll
  for (int u = 0; u < 8; ++u) {
    f32x4 w = *(const f32x4*)(lw + 128 + 16 * u + 4 * q);
    f32x2 wa; wa.x = w.x; wa.y = w.y;
    f32x2 wb; wb.x = w.z; wb.y = w.w;
    f32x4 y = acc[u];
    f32x2 lo; lo.x = fmaxf(y.x, 0.f); lo.y = fmaxf(y.y, 0.f);
    f32x2 hi; hi.x = fmaxf(y.z, 0.f); hi.y = fmaxf(y.w, 0.f);
    if (u & 1) { e2 = pk_fma(lo, wa, e2); e3 = pk_fma(hi, wb, e3); }
    else       { e0 = pk_fma(lo, wa, e0); e1 = pk_fma(hi, wb, e1); }
  }
  float d = (e0.x + e0.y) + (e1.x + e1.y) + ((e2.x + e2.y) + (e3.x + e3.y));
  d += __shfl_xor(d, 16);
  d += __shfl_xor(d, 32);
  return d + b3v;
}

// ---------- fast bf16 MFMA SDF eval (lazy per-slice B; b2/W3 from wave-private LDS) ----------
__device__ __forceinline__ float sdf_fast(float t,
    const bf16x8 (&w2f)[4][8], const f32x2 (&ap)[16], const f32x2 (&cp)[16],
    const float* lw, int q, float b3v)
{
  f32x2 t2; t2.x = t; t2.y = t;
  f32x4 acc[8];
  {
    U8 B;
    uint4 u4;
    u4.x = pack_relu_pair(pk_fma(cp[0], t2, ap[0]));
    u4.y = pack_relu_pair(pk_fma(cp[1], t2, ap[1]));
    u4.z = pack_relu_pair(pk_fma(cp[2], t2, ap[2]));
    u4.w = pack_relu_pair(pk_fma(cp[3], t2, ap[3]));
    B.u4 = u4;
    #pragma unroll
    for (int u = 0; u < 8; ++u) {   // b2 folded in as C operand (LDS, bit-identical values)
      f32x4 c = *(const f32x4*)(lw + 16 * u + 4 * q);
      acc[u] = __builtin_amdgcn_mfma_f32_16x16x32_bf16(w2f[0][u], B.v, c, 0, 0, 0);
    }
  }
  #pragma unroll
  for (int s = 1; s < 4; ++s) {
    U8 B;
    uint4 u4;
    u4.x = pack_relu_pair(pk_fma(cp[4*s+0], t2, ap[4*s+0]));
    u4.y = pack_relu_pair(pk_fma(cp[4*s+1], t2, ap[4*s+1]));
    u4.z = pack_relu_pair(pk_fma(cp[4*s+2], t2, ap[4*s+2]));
    u4.w = pack_relu_pair(pk_fma(cp[4*s+3], t2, ap[4*s+3]));
    B.u4 = u4;
    #pragma unroll
    for (int u = 0; u < 8; ++u)
      acc[u] = __builtin_amdgcn_mfma_f32_16x16x32_bf16(w2f[s][u], B.v, acc[u], 0, 0, 0);
  }
  return sdf_reduce(acc, lw, q, b3v);
}

// ---------- hi/lo-split precise eval (x100 tput channel) ----------
// Lazy per-slice HH/HL; identical MFMA accumulation order to the original.
__device__ __forceinline__ float sdf_precise(float t, int lane,
    const bf16x8 (&w2f)[4][8], const f32x2 (&ap)[16], const f32x2 (&cp)[16],
    const float* lw, int q, float b3v,
    const unsigned short* __restrict__ wlo)
{
  const bf16x8* wloF = (const bf16x8*)wlo;
  f32x4 acc[8];
  #pragma unroll
  for (int s = 0; s < 4; ++s) {
    U8 HH, HL;
    #pragma unroll
    for (int p = 0; p < 4; ++p) {
      float h0 = fmaxf(fmaf(cp[4*s+p].x, t, ap[4*s+p].x), 0.f);
      float h1 = fmaxf(fmaf(cp[4*s+p].y, t, ap[4*s+p].y), 0.f);
      unsigned short hb0 = f2bf(h0), hb1 = f2bf(h1);
      float r0 = h0 - __uint_as_float(((unsigned)hb0) << 16);
      float r1 = h1 - __uint_as_float(((unsigned)hb1) << 16);
      HH.us[2*p]     = hb0;      HH.us[2*p + 1] = hb1;
      HL.us[2*p]     = f2bf(r0); HL.us[2*p + 1] = f2bf(r1);
    }
    if (s == 0) {
      #pragma unroll
      for (int u = 0; u < 8; ++u) {
        f32x4 c = *(const f32x4*)(lw + 16 * u + 4 * q);
        acc[u] = __builtin_amdgcn_mfma_f32_16x16x32_bf16(w2f[0][u], HH.v, c, 0, 0, 0);
      }
    }
    #pragma unroll
    for (int u = 0; u < 8; ++u) {
      bf16x8 wl = wloF[(s * 8 + u) * 64 + lane];
      if (s > 0)
        acc[u] = __builtin_amdgcn_mfma_f32_16x16x32_bf16(w2f[s][u], HH.v, acc[u], 0, 0, 0);
      acc[u] = __builtin_amdgcn_mfma_f32_16x16x32_bf16(wl, HH.v, acc[u], 0, 0, 0);
      acc[u] = __builtin_amdgcn_mfma_f32_16x16x32_bf16(w2f[s][u], HL.v, acc[u], 0, 0, 0);
    }
  }
  return sdf_reduce(acc, lw, q, b3v);
}

// ---------- main: 1 wave = 16 rays; target 2 waves/SIMD, no cross-wave LDS ----------
__global__ __launch_bounds__(256, 2)
void render(const float* __restrict__ rays,
            const float* __restrict__ W1, const float* __restrict__ b1,
            const float* __restrict__ b2, const float* __restrict__ W3,
            const float* __restrict__ b3,
            const float* __restrict__ R1, const float* __restrict__ rb1,
            const float* __restrict__ R2, const float* __restrict__ rb2,
            const unsigned short* __restrict__ whi,
            const unsigned short* __restrict__ wlo,
            float* __restrict__ out, int nrays)
{
  // Per-wave PRIVATE copies: [0..127]=b2, [128..255]=W3. Each wave writes and
  // reads only its own 1KB region -> no __syncthreads, race-free by construction.
  __shared__ __align__(16) float lwb[4][256];

  const int tid  = threadIdx.x;
  const int lane = tid & 63;
  const int q    = lane >> 4;
  const int wv   = tid >> 6;
  const int ray  = blockIdx.x * 64 + wv * 16 + (lane & 15);

  float* lw = &lwb[wv][0];
  if (lane < 32) ((float4*)lw)[lane] = ((const float4*)b2)[lane];
  else           ((float4*)lw)[lane] = ((const float4*)W3)[lane - 32];
  // wave-internal ds_write -> ds_read ordering is enforced by lgkmcnt waits

  // W2^T hi fragments resident: 128 VGPRs
  bf16x8 w2f[4][8];
  const bf16x8* whiF = (const bf16x8*)whi;
  #pragma unroll
  for (int s = 0; s < 4; ++s)
    #pragma unroll
    for (int u = 0; u < 8; ++u)
      w2f[s][u] = whiF[(s * 8 + u) * 64 + lane];

  const float rox = rays[ray * 6 + 0];
  const float roy = rays[ray * 6 + 1];
  const float roz = rays[ray * 6 + 2];
  const float rdx = rays[ray * 6 + 3];
  const float rdy = rays[ray * 6 + 4];
  const float rdz = rays[ray * 6 + 5];
  const float b3v = b3[0];

  // a[k] = W1^T ro + b1, c[k] = W1^T rd  (fp32, register-resident, pair-packed)
  f32x2 ap[16], cp[16];
  #pragma unroll
  for (int s = 0; s < 4; ++s)
    #pragma unroll
    for (int p = 0; p < 4; ++p) {
      int k0 = 32 * s + 8 * q + 2 * p;
      int k1 = k0 + 1;
      float x0 = W1[k0], y0 = W1[HD + k0], z0 = W1[2 * HD + k0];
      float x1 = W1[k1], y1 = W1[HD + k1], z1 = W1[2 * HD + k1];
      f32x2 a, c;
      a.x = fmaf(x0, rox, fmaf(y0, roy, fmaf(z0, roz, b1[k0])));
      a.y = fmaf(x1, rox, fmaf(y1, roy, fmaf(z1, roz, b1[k1])));
      c.x = fmaf(x0, rdx, fmaf(y0, rdy, z0 * rdz));
      c.y = fmaf(x1, rdx, fmaf(y1, rdy, z1 * rdz));
      ap[4 * s + p] = a;
      cp[4 * s + p] = c;
    }

  // ---- sphere march (serial; break when all 16 rays hit) ----
  float cd = T_NEAR;
  bool hit = false;
  #pragma unroll 1
  for (int it = 0; it < MARCH_N; ++it) {
    float d = sdf_fast(cd, w2f, ap, cp, lw, q, b3v);
    bool nh = (d < HIT_EPS) && (cd >= T_NEAR) && (cd <= T_FAR);
    hit = hit || nh;
    cd = hit ? cd : cd + d;
    if (__ballot(!hit) == 0ull) break;
  }

  // ---- reflectance (exact fp32), split over 4 lane-quads ----
  const float ptx = fmaf(rdx, cd, rox);
  const float pty = fmaf(rdy, cd, roy);
  const float ptz = fmaf(rdz, cd, roz);
  float cr = 0.f, cg = 0.f, cb = 0.f;
  {
    int jb = q * 32;
    #pragma unroll 1
    for (int jj = 0; jj < 32; ++jj) {
      int j = jb + jj;
      float h = fmaf(R1[0 * HD + j], ptx,
                fmaf(R1[1 * HD + j], pty,
                fmaf(R1[2 * HD + j], ptz,
                fmaf(R1[3 * HD + j], rdx,
                fmaf(R1[4 * HD + j], rdy,
                fmaf(R1[5 * HD + j], rdz, rb1[j]))))));
      h = fmaxf(h, 0.f);
      cr = fmaf(h, R2[j * 3 + 0], cr);
      cg = fmaf(h, R2[j * 3 + 1], cg);
      cb = fmaf(h, R2[j * 3 + 2], cb);
    }
    cr += __shfl_xor(cr, 16); cr += __shfl_xor(cr, 32);
    cg += __shfl_xor(cg, 16); cg += __shfl_xor(cg, 32);
    cb += __shfl_xor(cb, 16); cb += __shfl_xor(cb, 32);
    cr += rb2[0]; cg += rb2[1]; cb += rb2[2];
  }

  // ---- tube scan: argmin of sdf over t = s*STEP, s = 0..32 ----
  float mn = sdf_fast(0.f, w2f, ap, cp, lw, q, b3v);
  int idx = 0;
  float ts = 0.f;
  #pragma unroll 1
  for (int s = 1; s <= TP_N; ++s) {
    ts += STEP;                       // exact (65*s/1024, s<=32)
    float d = sdf_fast(ts, w2f, ap, cp, lw, q, b3v);
    if (d < mn) { mn = d; idx = s; }
  }

  // ---- final tput at best t, hi/lo split ----
  const float tb = STEP * (float)idx;
  const float tput = sdf_precise(tb, lane, w2f, ap, cp, lw, q, b3v, wlo);

  if (q == 0) {
    float4 o;
    o.x = hit ? cr : 0.f;
    o.y = hit ? cg : 0.f;
    o.z = hit ? cb : 0.f;
    o.w = -ALPHA_C * tput;
    ((float4*)out)[ray] = o;
  }
}

extern "C" void kernel_launch(void* const* d_in, const int* in_sizes, int n_in,
                              void* d_out, int out_size, void* d_ws, size_t ws_size,
                              hipStream_t stream) {
  const float* rays = (const float*)d_in[0];
  const float* W1  = (const float*)d_in[1];
  const float* b1  = (const float*)d_in[2];
  const float* W2  = (const float*)d_in[3];
  const float* b2  = (const float*)d_in[4];
  const float* W3  = (const float*)d_in[5];
  const float* b3  = (const float*)d_in[6];
  const float* R1  = (const float*)d_in[7];
  const float* rb1 = (const float*)d_in[8];
  const float* R2  = (const float*)d_in[9];
  const float* rb2 = (const float*)d_in[10];

  unsigned short* whi = (unsigned short*)d_ws;   // 32 KB
  unsigned short* wlo = whi + 128 * 128;         // 32 KB

  const int nrays = in_sizes[0] / 6;

  hipLaunchKernelGGL(pack_w2, dim3(64), dim3(256), 0, stream, W2, whi, wlo);
  hipLaunchKernelGGL(render, dim3(nrays / 64), dim3(256), 0, stream,
                     rays, W1, b1, b2, W3, b3, R1, rb1, R2, rb2,
                     whi, wlo, (float*)d_out, nrays);
}

// Round 5
// 4228.427 us; speedup vs baseline: 1.2460x; 1.2460x over previous
//
#include <hip/hip_runtime.h>

typedef __attribute__((ext_vector_type(8))) short bf16x8;
typedef __attribute__((ext_vector_type(4))) float f32x4;
typedef __attribute__((ext_vector_type(2))) float f32x2;

constexpr int   HD      = 128;
constexpr float T_NEAR  = 0.2f;
constexpr float T_FAR   = 2.0f;
constexpr float ALPHA_C = 100.0f;
constexpr int   MARCH_N = 32;
constexpr float HIT_EPS = 0.005f;
constexpr int   TP_N    = 32;
constexpr float STEP    = 0.0634765625f;  // (2.0 + 0.5*(2/32))/32, exact

// ---------- bf16 helpers ----------
__device__ __forceinline__ unsigned short f2bf(float x) {
  unsigned u = __float_as_uint(x);
  unsigned r = 0x7fffu + ((u >> 16) & 1u);
  return (unsigned short)((u + r) >> 16);
}

union U8 { bf16x8 v; uint4 u4; unsigned short us[8]; };

// packed fp32 fma: d = a*b + c (VOP3P, 1 instr for 2 floats)
__device__ __forceinline__ f32x2 pk_fma(f32x2 a, f32x2 b, f32x2 c) {
  f32x2 d;
  asm("v_pk_fma_f32 %0, %1, %2, %3" : "=v"(d) : "v"(a), "v"(b), "v"(c));
  return d;
}

// {h.x,h.y} -> packed bf16 pair (round-half-up) with relu applied in bf16-bit
// domain (max_i16 vs 0 zeroes any negative bf16; sign-exact).
__device__ __forceinline__ unsigned pack_relu_pair(f32x2 h) {
  unsigned u0 = __float_as_uint(h.x) + 0x8000u;
  unsigned u1 = __float_as_uint(h.y) + 0x8000u;
  unsigned w, r;
  asm("v_perm_b32 %0, %1, %2, %3" : "=v"(w) : "v"(u1), "v"(u0), "s"(0x07060302u));
  asm("v_pk_max_i16 %0, %1, %2" : "=v"(r) : "v"(w), "v"(0u));
  return r;
}

// ---------- setup kernel: pack W2^T into per-lane MFMA A-fragments ----------
__global__ void pack_w2(const float* __restrict__ W2,
                        unsigned short* __restrict__ hi,
                        unsigned short* __restrict__ lo) {
  int idx = blockIdx.x * 256 + threadIdx.x;     // 0..16383
  int j = idx & 7, l = (idx >> 3) & 63, t = (idx >> 9) & 7, s = idx >> 12;
  int m = 16 * t + (l & 15);
  int k = 32 * s + (l >> 4) * 8 + j;
  float w = W2[k * HD + m];
  unsigned short h = f2bf(w);
  float hf = __uint_as_float(((unsigned)h) << 16);
  hi[idx] = h;
  lo[idx] = f2bf(w - hf);
}

// ---------- shared epilogue: relu + W3 dot + cross-quad reduce (bit-identical) ----------
__device__ __forceinline__ float sdf_reduce(const f32x4 (&acc)[8],
                                            const f32x2 (&w3p)[16], float b3v) {
  f32x2 e0; e0.x = 0.f; e0.y = 0.f;
  f32x2 e1 = e0, e2 = e0, e3 = e0;
  #pragma unroll
  for (int u = 0; u < 8; ++u) {
    f32x4 y = acc[u];
    f32x2 lo; lo.x = fmaxf(y.x, 0.f); lo.y = fmaxf(y.y, 0.f);
    f32x2 hi; hi.x = fmaxf(y.z, 0.f); hi.y = fmaxf(y.w, 0.f);
    if (u & 1) { e2 = pk_fma(lo, w3p[2*u], e2); e3 = pk_fma(hi, w3p[2*u+1], e3); }
    else       { e0 = pk_fma(lo, w3p[2*u], e0); e1 = pk_fma(hi, w3p[2*u+1], e1); }
  }
  float d = (e0.x + e0.y) + (e1.x + e1.y) + ((e2.x + e2.y) + (e3.x + e3.y));
  d += __shfl_xor(d, 16);
  d += __shfl_xor(d, 32);
  return d + b3v;
}

// ---------- fast eval: slices 0-1 A-frags in regs, slices 2-3 from LDS ----------
__device__ __forceinline__ float sdf_fast(float t,
    const bf16x8 (&w2r)[2][8], const unsigned short* lwhi, const float* lb2,
    const f32x2 (&ap)[16], const f32x2 (&cp)[16],
    const f32x2 (&w3p)[16], int q, int lane, float b3v)
{
  const bf16x8* lf = (const bf16x8*)lwhi + lane;  // LDS frag (s-2)*8+u at lf[f*64]
  f32x2 t2; t2.x = t; t2.y = t;
  f32x4 acc[8];
  {
    U8 B;
    uint4 u4;
    u4.x = pack_relu_pair(pk_fma(cp[0], t2, ap[0]));
    u4.y = pack_relu_pair(pk_fma(cp[1], t2, ap[1]));
    u4.z = pack_relu_pair(pk_fma(cp[2], t2, ap[2]));
    u4.w = pack_relu_pair(pk_fma(cp[3], t2, ap[3]));
    B.u4 = u4;
    #pragma unroll
    for (int u = 0; u < 8; ++u) {   // b2 folded in as C operand (LDS, bit-identical)
      f32x4 c = *(const f32x4*)(lb2 + 16 * u + 4 * q);
      acc[u] = __builtin_amdgcn_mfma_f32_16x16x32_bf16(w2r[0][u], B.v, c, 0, 0, 0);
    }
  }
  #pragma unroll
  for (int s = 1; s < 4; ++s) {
    U8 B;
    uint4 u4;
    u4.x = pack_relu_pair(pk_fma(cp[4*s+0], t2, ap[4*s+0]));
    u4.y = pack_relu_pair(pk_fma(cp[4*s+1], t2, ap[4*s+1]));
    u4.z = pack_relu_pair(pk_fma(cp[4*s+2], t2, ap[4*s+2]));
    u4.w = pack_relu_pair(pk_fma(cp[4*s+3], t2, ap[4*s+3]));
    B.u4 = u4;
    if (s == 1) {
      #pragma unroll
      for (int u = 0; u < 8; ++u)
        acc[u] = __builtin_amdgcn_mfma_f32_16x16x32_bf16(w2r[1][u], B.v, acc[u], 0, 0, 0);
    } else {
      #pragma unroll
      for (int u = 0; u < 8; ++u)
        acc[u] = __builtin_amdgcn_mfma_f32_16x16x32_bf16(lf[((s - 2) * 8 + u) * 64], B.v, acc[u], 0, 0, 0);
    }
  }
  return sdf_reduce(acc, w3p, b3v);
}

// ---------- hi/lo-split precise eval (x100 tput channel) ----------
// Lazy per-slice HH/HL; identical MFMA accumulation order to the original.
__device__ __forceinline__ float sdf_precise(float t, int lane,
    const bf16x8 (&w2r)[2][8], const unsigned short* lwhi, const float* lb2,
    const f32x2 (&ap)[16], const f32x2 (&cp)[16],
    const f32x2 (&w3p)[16], int q, float b3v,
    const unsigned short* __restrict__ wlo)
{
  const bf16x8* lf   = (const bf16x8*)lwhi + lane;
  const bf16x8* wloF = (const bf16x8*)wlo;
  f32x4 acc[8];
  #pragma unroll
  for (int s = 0; s < 4; ++s) {
    U8 HH, HL;
    #pragma unroll
    for (int p = 0; p < 4; ++p) {
      float h0 = fmaxf(fmaf(cp[4*s+p].x, t, ap[4*s+p].x), 0.f);
      float h1 = fmaxf(fmaf(cp[4*s+p].y, t, ap[4*s+p].y), 0.f);
      unsigned short hb0 = f2bf(h0), hb1 = f2bf(h1);
      float r0 = h0 - __uint_as_float(((unsigned)hb0) << 16);
      float r1 = h1 - __uint_as_float(((unsigned)hb1) << 16);
      HH.us[2*p]     = hb0;      HH.us[2*p + 1] = hb1;
      HL.us[2*p]     = f2bf(r0); HL.us[2*p + 1] = f2bf(r1);
    }
    if (s == 0) {
      #pragma unroll
      for (int u = 0; u < 8; ++u) {
        f32x4 c = *(const f32x4*)(lb2 + 16 * u + 4 * q);
        acc[u] = __builtin_amdgcn_mfma_f32_16x16x32_bf16(w2r[0][u], HH.v, c, 0, 0, 0);
      }
    }
    #pragma unroll
    for (int u = 0; u < 8; ++u) {
      bf16x8 wh = (s < 2) ? w2r[s][u] : lf[((s - 2) * 8 + u) * 64];
      bf16x8 wl = wloF[(s * 8 + u) * 64 + lane];
      if (s > 0)
        acc[u] = __builtin_amdgcn_mfma_f32_16x16x32_bf16(wh, HH.v, acc[u], 0, 0, 0);
      acc[u] = __builtin_amdgcn_mfma_f32_16x16x32_bf16(wl, HH.v, acc[u], 0, 0, 0);
      acc[u] = __builtin_amdgcn_mfma_f32_16x16x32_bf16(wh, HL.v, acc[u], 0, 0, 0);
    }
  }
  return sdf_reduce(acc, w3p, b3v);
}

// ---------- main: 1 wave = 16 rays; half of W2-hi in LDS via BENIGN DUPLICATE
// staging (every wave writes the same bytes; no __syncthreads, no cross-wave
// dependency -> deterministic under any wave schedule). 2 waves/SIMD. ----------
__global__ __launch_bounds__(256, 2)
void render(const float* __restrict__ rays,
            const float* __restrict__ W1, const float* __restrict__ b1,
            const float* __restrict__ b2, const float* __restrict__ W3,
            const float* __restrict__ b3,
            const float* __restrict__ R1, const float* __restrict__ rb1,
            const float* __restrict__ R2, const float* __restrict__ rb2,
            const unsigned short* __restrict__ whi,
            const unsigned short* __restrict__ wlo,
            float* __restrict__ out, int nrays)
{
  // Slices 2,3 of W2-hi fragments (16 KB) + b2 (512 B). Written identically by
  // every wave from the same global source; each wave reads only after its own
  // writes (lgkmcnt-ordered) -> race-free by value.
  __shared__ __align__(16) unsigned short lwhi[HD * HD / 2];
  __shared__ __align__(16) float lb2[HD];

  const int tid  = threadIdx.x;
  const int lane = tid & 63;
  const int q    = lane >> 4;
  const int wv   = tid >> 6;
  const int ray  = blockIdx.x * 64 + wv * 16 + (lane & 15);

  // ---- per-wave duplicate staging (no barrier) ----
  {
    const uint4* src = (const uint4*)whi + 1024;   // shorts [8192..16384) = slices 2,3
    uint4*       dst = (uint4*)lwhi;
    #pragma unroll
    for (int i = 0; i < 16; ++i)
      dst[lane + 64 * i] = src[lane + 64 * i];
    if (lane < 32)
      ((float4*)lb2)[lane] = ((const float4*)b2)[lane];
  }

  // W2^T hi fragments, slices 0,1 resident in registers: 64 VGPRs
  bf16x8 w2r[2][8];
  const bf16x8* whiF = (const bf16x8*)whi;
  #pragma unroll
  for (int s = 0; s < 2; ++s)
    #pragma unroll
    for (int u = 0; u < 8; ++u)
      w2r[s][u] = whiF[(s * 8 + u) * 64 + lane];

  const float rox = rays[ray * 6 + 0];
  const float roy = rays[ray * 6 + 1];
  const float roz = rays[ray * 6 + 2];
  const float rdx = rays[ray * 6 + 3];
  const float rdy = rays[ray * 6 + 4];
  const float rdz = rays[ray * 6 + 5];
  const float b3v = b3[0];

  // a[k] = W1^T ro + b1, c[k] = W1^T rd  (fp32, register-resident, pair-packed)
  f32x2 ap[16], cp[16];
  #pragma unroll
  for (int s = 0; s < 4; ++s)
    #pragma unroll
    for (int p = 0; p < 4; ++p) {
      int k0 = 32 * s + 8 * q + 2 * p;
      int k1 = k0 + 1;
      float x0 = W1[k0], y0 = W1[HD + k0], z0 = W1[2 * HD + k0];
      float x1 = W1[k1], y1 = W1[HD + k1], z1 = W1[2 * HD + k1];
      f32x2 a, c;
      a.x = fmaf(x0, rox, fmaf(y0, roy, fmaf(z0, roz, b1[k0])));
      a.y = fmaf(x1, rox, fmaf(y1, roy, fmaf(z1, roz, b1[k1])));
      c.x = fmaf(x0, rdx, fmaf(y0, rdy, z0 * rdz));
      c.y = fmaf(x1, rdx, fmaf(y1, rdy, z1 * rdz));
      ap[4 * s + p] = a;
      cp[4 * s + p] = c;
    }

  // W3 as fp32 pairs in registers (reduce tail is latency-exposed)
  f32x2 w3p[16];
  #pragma unroll
  for (int u = 0; u < 8; ++u) {
    int n0 = 16 * u + 4 * q;
    f32x2 wa; wa.x = W3[n0];     wa.y = W3[n0 + 1];
    f32x2 wb; wb.x = W3[n0 + 2]; wb.y = W3[n0 + 3];
    w3p[2 * u] = wa; w3p[2 * u + 1] = wb;
  }

  // ---- sphere march (serial; break when all 16 rays hit) ----
  float cd = T_NEAR;
  bool hit = false;
  #pragma unroll 1
  for (int it = 0; it < MARCH_N; ++it) {
    float d = sdf_fast(cd, w2r, lwhi, lb2, ap, cp, w3p, q, lane, b3v);
    bool nh = (d < HIT_EPS) && (cd >= T_NEAR) && (cd <= T_FAR);
    hit = hit || nh;
    cd = hit ? cd : cd + d;
    if (__ballot(!hit) == 0ull) break;
  }

  // ---- reflectance (exact fp32), split over 4 lane-quads ----
  const float ptx = fmaf(rdx, cd, rox);
  const float pty = fmaf(rdy, cd, roy);
  const float ptz = fmaf(rdz, cd, roz);
  float cr = 0.f, cg = 0.f, cb = 0.f;
  {
    int jb = q * 32;
    #pragma unroll 1
    for (int jj = 0; jj < 32; ++jj) {
      int j = jb + jj;
      float h = fmaf(R1[0 * HD + j], ptx,
                fmaf(R1[1 * HD + j], pty,
                fmaf(R1[2 * HD + j], ptz,
                fmaf(R1[3 * HD + j], rdx,
                fmaf(R1[4 * HD + j], rdy,
                fmaf(R1[5 * HD + j], rdz, rb1[j]))))));
      h = fmaxf(h, 0.f);
      cr = fmaf(h, R2[j * 3 + 0], cr);
      cg = fmaf(h, R2[j * 3 + 1], cg);
      cb = fmaf(h, R2[j * 3 + 2], cb);
    }
    cr += __shfl_xor(cr, 16); cr += __shfl_xor(cr, 32);
    cg += __shfl_xor(cg, 16); cg += __shfl_xor(cg, 32);
    cb += __shfl_xor(cb, 16); cb += __shfl_xor(cb, 32);
    cr += rb2[0]; cg += rb2[1]; cb += rb2[2];
  }

  // ---- tube scan: argmin of sdf over t = s*STEP, s = 0..32 ----
  float mn = sdf_fast(0.f, w2r, lwhi, lb2, ap, cp, w3p, q, lane, b3v);
  int idx = 0;
  float ts = 0.f;
  #pragma unroll 1
  for (int s = 1; s <= TP_N; ++s) {
    ts += STEP;                       // exact (65*s/1024, s<=32)
    float d = sdf_fast(ts, w2r, lwhi, lb2, ap, cp, w3p, q, lane, b3v);
    if (d < mn) { mn = d; idx = s; }
  }

  // ---- final tput at best t, hi/lo split ----
  const float tb = STEP * (float)idx;
  const float tput = sdf_precise(tb, lane, w2r, lwhi, lb2, ap, cp, w3p, q, b3v, wlo);

  if (q == 0) {
    float4 o;
    o.x = hit ? cr : 0.f;
    o.y = hit ? cg : 0.f;
    o.z = hit ? cb : 0.f;
    o.w = -ALPHA_C * tput;
    ((float4*)out)[ray] = o;
  }
}

extern "C" void kernel_launch(void* const* d_in, const int* in_sizes, int n_in,
                              void* d_out, int out_size, void* d_ws, size_t ws_size,
                              hipStream_t stream) {
  const float* rays = (const float*)d_in[0];
  const float* W1  = (const float*)d_in[1];
  const float* b1  = (const float*)d_in[2];
  const float* W2  = (const float*)d_in[3];
  const float* b2  = (const float*)d_in[4];
  const float* W3  = (const float*)d_in[5];
  const float* b3  = (const float*)d_in[6];
  const float* R1  = (const float*)d_in[7];
  const float* rb1 = (const float*)d_in[8];
  const float* R2  = (const float*)d_in[9];
  const float* rb2 = (const float*)d_in[10];

  unsigned short* whi = (unsigned short*)d_ws;   // 32 KB
  unsigned short* wlo = whi + 128 * 128;         // 32 KB

  const int nrays = in_sizes[0] / 6;

  hipLaunchKernelGGL(pack_w2, dim3(64), dim3(256), 0, stream, W2, whi, wlo);
  hipLaunchKernelGGL(render, dim3(nrays / 64), dim3(256), 0, stream,
                     rays, W1, b1, b2, W3, b3, R1, rb1, R2, rb2,
                     whi, wlo, (float*)d_out, nrays);
}